// Round 6
// baseline (169.674 us; speedup 1.0000x reference)
//
#include <hip/hip_runtime.h>
#include <hip/hip_bf16.h>

typedef short short8 __attribute__((ext_vector_type(8)));
typedef short short4v __attribute__((ext_vector_type(4)));
typedef float f32x4 __attribute__((ext_vector_type(4)));

// Workspace byte offsets
#define WF_OFF  0u         // bf16 wfrag[t=27][ot=2][lane=64][j=8] = 55296 B
#define RWB_OFF 55296u     // f32 rw_sum[b]*bias_sum[o] : [8][32] = 1024 B
#define RWS_OFF 56320u     // f32 rw_sum[8] = 32 B
#define ZP_OFF  57344u     // 4096 B zero page (y-halo DMA source)
#define XB_OFF  65536u     // bf16 x in plane-tile layout: [b][z][y][X][c-slot] = 33554432 B
#define XB_BYTES 33554432u

// Plane-tile row layout (per (b,z,y)): 64 X-columns x 64 B c-row.
// c-row = 8 slots x 8 B (4 consecutive c as bf16), slot' = c4 ^ ((X>>2)&7).
// Frag reads at stride-64B rows land 2 lanes/bank-pair (free, m136) thanks to
// the slot XOR; staging writes don't exist (DMA) -> no write-side conflicts.

__device__ __forceinline__ unsigned bf16rne(float f) {
    unsigned u = __float_as_uint(f);
    return (u + 0x7FFFu + ((u >> 16) & 1u)) >> 16;
}

__device__ __forceinline__ void llds16(const void* g, void* l) {
    __builtin_amdgcn_global_load_lds(
        (const __attribute__((address_space(1))) unsigned int*)g,
        (__attribute__((address_space(3))) unsigned int*)l, 16, 0, 0);
}

// ---------------------------------------------------------------------------
// Prep: wfrag in MFMA A-operand layout; rwb_bias; rw_sum. (unchanged, proven)
// ---------------------------------------------------------------------------
__global__ void condconv_prep(const float* __restrict__ rw,      // [8,8]
                              const float* __restrict__ weight,  // [8,32,32,27]
                              const float* __restrict__ bias,    // [8,32]
                              char* __restrict__ ws) {
    int i = blockIdx.x * 256 + threadIdx.x;
    if (i < 27648) {
        int t   = i >> 10;
        int rem = i & 1023;
        int ot  = rem >> 9;
        int l   = (rem >> 3) & 63;
        int j   = rem & 7;
        int o   = ot * 16 + (l & 15);
        int c   = 8 * (l >> 4) + j;
        float s = 0.f;
#pragma unroll
        for (int e = 0; e < 8; ++e) s += weight[((e * 32 + o) * 32 + c) * 27 + t];
        ((unsigned short*)(ws + WF_OFF))[i] = (unsigned short)bf16rne(s);
    } else if (i < 27904) {
        int k = i - 27648;
        int b = k >> 5, o = k & 31;
        float rs = 0.f, bs = 0.f;
#pragma unroll
        for (int e = 0; e < 8; ++e) { rs += rw[b * 8 + e]; bs += bias[e * 32 + o]; }
        ((float*)(ws + RWB_OFF))[k] = rs * bs;
        if (o == 0) ((float*)(ws + RWS_OFF))[b] = rs;
    }
}

// ---------------------------------------------------------------------------
// xform: x fp32 [8,32,16,64,64] -> bf16 plane-tile layout at ws+XB_OFF.
// Block = one (b, z, y-octet): 8 rows x 4096 B. Also zeroes the zero page.
// ---------------------------------------------------------------------------
__global__ __launch_bounds__(256) void condconv_xform(
        const float* __restrict__ x, char* __restrict__ ws) {
    const int tid = threadIdx.x;
    if (blockIdx.x == 0)
        *(uint4*)(ws + ZP_OFF + tid * 16) = make_uint4(0, 0, 0, 0);

    const int yo = blockIdx.x & 7;
    const int z  = (blockIdx.x >> 3) & 15;
    const int b  = blockIdx.x >> 7;
    const float* xb = x + (size_t)b * 2097152;
    char* xrow0 = ws + XB_OFF + ((size_t)(b * 16 + z) * 64 + yo * 8) * 4096;

#pragma unroll
    for (int it = 0; it < 4; ++it) {
        const int s  = it * 256 + tid;
        const int x4 = s & 15;
        const int c4 = (s >> 4) & 7;
        const int yr = s >> 7;                 // 0..7
        const int y  = yo * 8 + yr;
        const float* p = xb + (size_t)c4 * 262144 + z * 4096 + y * 64 + 4 * x4;
        float4 v0 = *(const float4*)(p);
        float4 v1 = *(const float4*)(p + 65536);
        float4 v2 = *(const float4*)(p + 131072);
        float4 v3 = *(const float4*)(p + 196608);
        const float a0[4] = {v0.x, v0.y, v0.z, v0.w};
        const float a1[4] = {v1.x, v1.y, v1.z, v1.w};
        const float a2[4] = {v2.x, v2.y, v2.z, v2.w};
        const float a3[4] = {v3.x, v3.y, v3.z, v3.w};
        char* rowp = xrow0 + (size_t)yr * 4096;
        const int slot = c4 ^ (x4 & 7);
#pragma unroll
        for (int xi = 0; xi < 4; ++xi) {
            union { __hip_bfloat162 h2[2]; uint2 u; } g;
            g.h2[0] = __float22bfloat162_rn(make_float2(a0[xi], a1[xi]));
            g.h2[1] = __float22bfloat162_rn(make_float2(a2[xi], a3[xi]));
            *(uint2*)(rowp + (4 * x4 + xi) * 64 + slot * 8) = g.u;
        }
    }
}

// ---------------------------------------------------------------------------
// Fused conv, z-plane phased, y-tile 8, DMA staging.
// Per dz-phase: 10 global_load_lds dwordx4 per wave (zero VALU staging) into a
// linear 40 KB LDS plane, barrier (drains vmcnt), then 144 MFMA/wave.
// y-halo rows DMA from zero page; X-halo via clamped read + cndmask zero.
// XCD-bijective swizzle: each XCD owns one b, z-fastest -> bf16[b] (4 MB)
// L2-resident -> fused HBM fetch ~= compulsory 33.5 MB.
// ---------------------------------------------------------------------------
__global__ __launch_bounds__(256, 3) void condconv_fused_dma(
        const char* __restrict__ ws,     // workspace base
        float* __restrict__ out) {
    __shared__ __align__(16) char smem[40960];   // 10 rows x 4096 B

    const int tid  = threadIdx.x;
    const int wv   = tid >> 6;
    const int lane = tid & 63;
    const int n    = lane & 15;
    const int quad = lane >> 4;

    // 1024 blocks: xcd = hw&7 owns logical [xcd*128, xcd*128+128) = one b,
    // ordered z-fastest (16 z per y-tile) for L2 plane reuse.
    const int logical = (blockIdx.x & 7) * 128 + (blockIdx.x >> 3);
    const int z  = logical & 15;
    const int y0 = ((logical >> 4) & 7) * 8;
    const int b  = logical >> 7;
    const int xn = wv * 16 + n;

    f32x4 acc[2][8] = {};                          // [o-tile][y-row r]
    const char* wbase = ws + WF_OFF + lane * 16;
    const char* xb16  = ws + XB_OFF + (size_t)(b * 16) * 64 * 4096;
    const char* zp    = ws + ZP_OFF;

#pragma unroll
    for (int dz = 0; dz < 3; ++dz) {
        const int gz = z + dz - 1;
        const bool gzok = (unsigned)gz < 16u;

        __syncthreads();   // previous phase's LDS reads done before overwrite
        if (gzok) {
            const char* pb = xb16 + (size_t)gz * 64 * 4096;
            const int lo = wv * 1024 + lane * 16;
#pragma unroll
            for (int yp = 0; yp < 10; ++yp) {
                const int gy = y0 + yp - 1;
                const char* src = ((unsigned)gy < 64u) ? (pb + (size_t)gy * 4096 + lo)
                                                       : (zp + lo);
                llds16(src, smem + yp * 4096 + wv * 1024);
            }
        }
        __syncthreads();   // drains vmcnt -> plane ready

        if (gzok) {
            short8 wreg[18];                       // this dz's 9 taps x 2 o-tiles
            const char* wp = wbase + dz * 18432;
#pragma unroll
            for (int t = 0; t < 18; ++t) wreg[t] = *(const short8*)(wp + t * 1024);
#pragma unroll
            for (int yq = 0; yq < 10; ++yq) {
#pragma unroll
                for (int dx = 0; dx < 3; ++dx) {
                    const int X  = xn + dx - 1;
                    const bool ok = (unsigned)X < 64u;
                    const int Xc = ok ? X : 0;
                    const char* rowp = smem + yq * 4096 + Xc * 64;
                    const int s8 = (Xc >> 2) & 7;
                    union { short8 v; short4v h[2]; } xf;
                    xf.h[0] = *(const short4v*)(rowp + (((2 * quad + 0) ^ s8) << 3));
                    xf.h[1] = *(const short4v*)(rowp + (((2 * quad + 1) ^ s8) << 3));
                    if (!ok) { xf.h[0] = short4v{0, 0, 0, 0}; xf.h[1] = short4v{0, 0, 0, 0}; }
#pragma unroll
                    for (int dy = 0; dy < 3; ++dy) {
                        const int r = yq - dy;
                        if (r >= 0 && r < 8) {
                            acc[0][r] = __builtin_amdgcn_mfma_f32_16x16x32_bf16(
                                wreg[(dy * 3 + dx) * 2 + 0], xf.v, acc[0][r], 0, 0, 0);
                            acc[1][r] = __builtin_amdgcn_mfma_f32_16x16x32_bf16(
                                wreg[(dy * 3 + dx) * 2 + 1], xf.v, acc[1][r], 0, 0, 0);
                        }
                    }
                }
            }
        }
    }

    // ---- epilogue: out = rw_sum[b]*acc + rw_sum[b]*bias_sum[o] ----
    const float rwb = ((const float*)(ws + RWS_OFF))[b];
    const float* rwbias = (const float*)(ws + RWB_OFF);
#pragma unroll
    for (int ot = 0; ot < 2; ++ot)
#pragma unroll
        for (int reg = 0; reg < 4; ++reg) {
            const int o = ot * 16 + quad * 4 + reg;
            const float bb = rwbias[b * 32 + o];
            const size_t obase = ((size_t)(b * 32 + o) * 16 + z) * 64;
#pragma unroll
            for (int r = 0; r < 8; ++r)
                out[(obase + y0 + r) * 64 + xn] = rwb * acc[ot][r][reg] + bb;
        }
}

// ---------------------------------------------------------------------------
// Fallback (proven 62.5 us R0 kernel) when ws too small for XB.
// ---------------------------------------------------------------------------
#define XS 72
#define RS (66 * XS)
#define PLANE (10 * RS)

__global__ __launch_bounds__(256, 3) void condconv_fused_v0(
        const float* __restrict__ x, const char* __restrict__ wf,
        const float* __restrict__ rwbias, const float* __restrict__ rwsum,
        float* __restrict__ out) {
    __shared__ __align__(16) char smem[PLANE];
    const int tid  = threadIdx.x;
    const int wv   = tid >> 6;
    const int lane = tid & 63;
    const int n    = lane & 15;
    const int quad = lane >> 4;
    const int y0   = blockIdx.x * 8;
    const int z    = blockIdx.y;
    const int b    = blockIdx.z;
    const int xn   = wv * 16 + n;

    if (tid < 80) {
        int yp = tid >> 3, side = (tid >> 2) & 1, q = tid & 3;
        *(uint4*)(smem + yp * RS + side * (65 * XS) + q * 16) = make_uint4(0, 0, 0, 0);
    }

    f32x4 acc[2][8] = {};
    const float* xb = x + (size_t)b * 2097152;
    const char* wbase = wf + lane * 16;

#pragma unroll
    for (int dz = 0; dz < 3; ++dz) {
        const int gz = z + dz - 1;
        const bool gzok = (unsigned)gz < 16u;
        __syncthreads();
        if (gzok) {
#pragma unroll
            for (int it = 0; it < 5; ++it) {
                const int s  = it * 256 + tid;
                const int x4 = s & 15;
                const int c4 = (s >> 4) & 7;
                const int yp = s >> 7;
                const int gy = y0 + yp - 1;
                float4 v0 = {0, 0, 0, 0}, v1 = v0, v2 = v0, v3 = v0;
                if ((unsigned)gy < 64u) {
                    const float* p = xb + (size_t)c4 * 262144 + gz * 4096 + gy * 64 + 4 * x4;
                    v0 = *(const float4*)(p);
                    v1 = *(const float4*)(p + 65536);
                    v2 = *(const float4*)(p + 131072);
                    v3 = *(const float4*)(p + 196608);
                }
                const float a0[4] = {v0.x, v0.y, v0.z, v0.w};
                const float a1[4] = {v1.x, v1.y, v1.z, v1.w};
                const float a2[4] = {v2.x, v2.y, v2.z, v2.w};
                const float a3[4] = {v3.x, v3.y, v3.z, v3.w};
#pragma unroll
                for (int xi = 0; xi < 4; ++xi) {
                    union { __hip_bfloat162 h2[2]; uint2 u; } g;
                    g.h2[0] = __float22bfloat162_rn(make_float2(a0[xi], a1[xi]));
                    g.h2[1] = __float22bfloat162_rn(make_float2(a2[xi], a3[xi]));
                    const int X = 4 * x4 + xi + 1;
                    const int slot = c4 ^ ((X >> 2) & 7);
                    *(uint2*)(smem + yp * RS + X * XS + slot * 8) = g.u;
                }
            }
        }
        __syncthreads();
        if (gzok) {
            short8 wreg[18];
            const char* wp = wbase + dz * 18432;
#pragma unroll
            for (int t = 0; t < 18; ++t) wreg[t] = *(const short8*)(wp + t * 1024);
#pragma unroll
            for (int yq = 0; yq < 10; ++yq) {
#pragma unroll
                for (int dx = 0; dx < 3; ++dx) {
                    const int X = xn + dx;
                    const char* rowp = smem + yq * RS + X * XS;
                    const int s8 = (X >> 2) & 7;
                    union { short8 v; short4v h[2]; } xf;
                    xf.h[0] = *(const short4v*)(rowp + (((2 * quad + 0) ^ s8) << 3));
                    xf.h[1] = *(const short4v*)(rowp + (((2 * quad + 1) ^ s8) << 3));
#pragma unroll
                    for (int dy = 0; dy < 3; ++dy) {
                        const int r = yq - dy;
                        if (r >= 0 && r < 8) {
                            acc[0][r] = __builtin_amdgcn_mfma_f32_16x16x32_bf16(
                                wreg[(dy * 3 + dx) * 2 + 0], xf.v, acc[0][r], 0, 0, 0);
                            acc[1][r] = __builtin_amdgcn_mfma_f32_16x16x32_bf16(
                                wreg[(dy * 3 + dx) * 2 + 1], xf.v, acc[1][r], 0, 0, 0);
                        }
                    }
                }
            }
        }
    }

    const float rwb = rwsum[b];
#pragma unroll
    for (int ot = 0; ot < 2; ++ot)
#pragma unroll
        for (int reg = 0; reg < 4; ++reg) {
            const int o = ot * 16 + quad * 4 + reg;
            const float bb = rwbias[b * 32 + o];
            const size_t obase = ((size_t)(b * 32 + o) * 16 + z) * 64;
#pragma unroll
            for (int r = 0; r < 8; ++r)
                out[(obase + y0 + r) * 64 + xn] = rwb * acc[ot][r][reg] + bb;
        }
}

// ---------------------------------------------------------------------------
extern "C" void kernel_launch(void* const* d_in, const int* in_sizes, int n_in,
                              void* d_out, int out_size, void* d_ws, size_t ws_size,
                              hipStream_t stream) {
    const float* x      = (const float*)d_in[0];  // [8,32,16,64,64]
    const float* rw     = (const float*)d_in[1];  // [8,8]
    const float* weight = (const float*)d_in[2];  // [8,32,32,27]
    const float* bias   = (const float*)d_in[3];  // [8,32]
    float* out = (float*)d_out;
    char*  ws  = (char*)d_ws;

    condconv_prep<<<109, 256, 0, stream>>>(rw, weight, bias, ws);

    if (ws_size >= (size_t)XB_OFF + XB_BYTES) {
        condconv_xform<<<1024, 256, 0, stream>>>(x, ws);
        condconv_fused_dma<<<1024, 256, 0, stream>>>(ws, out);
    } else {
        condconv_fused_v0<<<dim3(8, 16, 8), 256, 0, stream>>>(
            x, ws + WF_OFF,
            (const float*)(ws + RWB_OFF), (const float*)(ws + RWS_OFF), out);
    }
}

// Round 8
// 148.939 us; speedup vs baseline: 1.1392x; 1.1392x over previous
//
#include <hip/hip_runtime.h>
#include <hip/hip_bf16.h>

typedef short short8 __attribute__((ext_vector_type(8)));
typedef short short4v __attribute__((ext_vector_type(4)));
typedef float f32x4 __attribute__((ext_vector_type(4)));

// Workspace byte offsets
#define WF_OFF  0u        // bf16 wfrag[t=27][ot=2][lane=64][j=8] = 55296 B
#define RWB_OFF 55296u    // f32 rw_sum[b]*bias_sum[o] : [8][32] = 1024 B
#define RWS_OFF 56320u    // f32 rw_sum[8] = 32 B

// Ring-3 LDS planes. Plane = 10 y-rows x 24 X-cols x 72 B (64 B data = 8
// c-slots of 8 B, 8 B pad for write-bank spread; slot' = c4 ^ (lx>>2)).
#define XSB 72
#define ROWB (24 * XSB)        // 1728 B
#define PLANE_B (10 * ROWB)    // 17280 B
#define RING_B (3 * PLANE_B)   // 51840 B

__device__ __forceinline__ unsigned bf16rne(float f) {
    unsigned u = __float_as_uint(f);
    return (u + 0x7FFFu + ((u >> 16) & 1u)) >> 16;
}

// ---------------------------------------------------------------------------
// Prep: wfrag in MFMA A-operand layout; rwb_bias; rw_sum. (unchanged, proven)
// A-frag (16x16x32 bf16): lane l holds A[m=l&15][k=8*(l>>4)+j], j=0..7.
// wfrag byte addr = (dz*9+dy*3+dx)*2048 + ot*1024 + lane*16.
// ---------------------------------------------------------------------------
__global__ void condconv_prep(const float* __restrict__ rw,      // [8,8]
                              const float* __restrict__ weight,  // [8,32,32,27]
                              const float* __restrict__ bias,    // [8,32]
                              char* __restrict__ ws) {
    int i = blockIdx.x * 256 + threadIdx.x;
    if (i < 27648) {
        int t   = i >> 10;
        int rem = i & 1023;
        int ot  = rem >> 9;
        int l   = (rem >> 3) & 63;
        int j   = rem & 7;
        int o   = ot * 16 + (l & 15);
        int c   = 8 * (l >> 4) + j;
        float s = 0.f;
#pragma unroll
        for (int e = 0; e < 8; ++e) s += weight[((e * 32 + o) * 32 + c) * 27 + t];
        ((unsigned short*)(ws + WF_OFF))[i] = (unsigned short)bf16rne(s);
    } else if (i < 27904) {
        int k = i - 27648;
        int b = k >> 5, o = k & 31;
        float rs = 0.f, bs = 0.f;
#pragma unroll
        for (int e = 0; e < 8; ++e) { rs += rw[b * 8 + e]; bs += bias[e * 32 + o]; }
        ((float*)(ws + RWB_OFF))[k] = rs * bs;
        if (o == 0) ((float*)(ws + RWS_OFF))[b] = rs;
    }
}

// ---------------------------------------------------------------------------
// Single-pass z-walk conv. Block = (b, y8, x16, z-half); walks 8 z-steps.
// Ring-3 LDS planes: per step stage ONE plane (zi+1), compute output zi from
// planes zi-1, zi, zi+1. 2 barriers/z-output (was 6); staging 1.25 planes per
// output (was 3). wreg[27] hoisted (loop-invariant). Waves = (ot, y-half):
// acc = 4 x f32x4 only. XCD swizzle: each XCD owns one b; its 64 blocks walk
// z in lockstep -> 3-plane working set ~1.6 MB stays L2-resident.
// ---------------------------------------------------------------------------
__global__ __launch_bounds__(256, 2) void condconv_zwalk(
        const float* __restrict__ x,     // [8,32,16,64,64] fp32
        const char* __restrict__ wf,     // ws + WF_OFF
        const float* __restrict__ rwbias,
        const float* __restrict__ rwsum,
        float* __restrict__ out) {
    __shared__ __align__(16) char smem[RING_B];

    const int tid  = threadIdx.x;
    const int wv   = tid >> 6;
    const int lane = tid & 63;
    const int n    = lane & 15;
    const int quad = lane >> 4;
    const int ot   = wv & 1;
    const int yh   = wv >> 1;

    // 512 blocks, bijective XCD swizzle (512 % 8 == 0): logical b outermost.
    const int logical = (blockIdx.x & 7) * 64 + (blockIdx.x >> 3);
    const int b   = logical >> 6;
    const int rem = logical & 63;
    const int zb  = rem & 1;               // z-half fastest: halves co-run
    const int xb  = (rem >> 1) & 3;
    const int yb  = rem >> 3;
    const int y0 = yb * 8, x0 = xb * 16, zr0 = zb * 8;

    const float* xbp = x + (size_t)b * 2097152;   // 32*16*64*64

    // ---- staging indices (loop-invariant). 240 active threads:
    // s = {c4h(4) , yp(10), x4(6)}; thread covers 4 x-cols x 8 c (c4h, c4h+4).
    const bool sact = tid < 240;
    const int  sx4  = tid % 6;                    // x-quad within 24-col tile
    const int  syp  = (tid / 6) % 10;             // plane row
    const int  sc4h = tid / 60;                   // 0..3 -> c4 = sc4h, sc4h+4
    const int  gxq  = xb * 4 + sx4 - 1;           // global x-quad (may be OOB)
    const int  gy   = y0 + syp - 1;
    const bool gok  = ((unsigned)gxq < 16u) && ((unsigned)gy < 64u);
    // fp32 element offset within batch (valid only when gok)
    const long soff = (long)sc4h * 262144 + (long)(gok ? gy : 0) * 64 +
                      (long)(gok ? gxq : 0) * 4;
    // LDS write offsets within plane (A: c4=sc4h, B: c4=sc4h+4)
    const int woffA = syp * ROWB + (4 * sx4) * XSB + ((sc4h ^ sx4) << 3);
    const int woffB = syp * ROWB + (4 * sx4) * XSB + (((sc4h + 4) ^ sx4) << 3);

    // ---- hoisted weight fragments: 27 taps for this wave's o-tile.
    short8 wreg[27];
    {
        const char* wb_ = wf + lane * 16 + ot * 1024;
#pragma unroll
        for (int t = 0; t < 27; ++t) wreg[t] = *(const short8*)(wb_ + t * 2048);
    }

    // ---- epilogue constants
    const float rwb = rwsum[b];
    float bb[4];
#pragma unroll
    for (int j = 0; j < 4; ++j) bb[j] = rwbias[b * 32 + ot * 16 + quad * 4 + j];
    float* outb = out + (size_t)(b * 32 + ot * 16 + quad * 4) * 65536 +
                  (size_t)(y0 + yh * 4) * 64 + x0 + n;

    // ---- stage plane p (z index; OOB -> zeros) into ring slot `pl`.
    auto STAGE = [&](int p, char* pl) {
        if (!sact) return;
        float4 vA0 = {0,0,0,0}, vA1 = vA0, vA2 = vA0, vA3 = vA0;
        float4 vB0 = vA0, vB1 = vA0, vB2 = vA0, vB3 = vA0;
        if (gok && (unsigned)p < 16u) {
            const float* q0 = xbp + soff + (long)p * 4096;
            vA0 = *(const float4*)(q0);
            vA1 = *(const float4*)(q0 + 65536);
            vA2 = *(const float4*)(q0 + 131072);
            vA3 = *(const float4*)(q0 + 196608);
            const float* q1 = q0 + 1048576;       // +16 c-planes
            vB0 = *(const float4*)(q1);
            vB1 = *(const float4*)(q1 + 65536);
            vB2 = *(const float4*)(q1 + 131072);
            vB3 = *(const float4*)(q1 + 196608);
        }
        const float A0[4] = {vA0.x, vA0.y, vA0.z, vA0.w};
        const float A1[4] = {vA1.x, vA1.y, vA1.z, vA1.w};
        const float A2[4] = {vA2.x, vA2.y, vA2.z, vA2.w};
        const float A3[4] = {vA3.x, vA3.y, vA3.z, vA3.w};
        const float B0[4] = {vB0.x, vB0.y, vB0.z, vB0.w};
        const float B1[4] = {vB1.x, vB1.y, vB1.z, vB1.w};
        const float B2[4] = {vB2.x, vB2.y, vB2.z, vB2.w};
        const float B3[4] = {vB3.x, vB3.y, vB3.z, vB3.w};
#pragma unroll
        for (int xi = 0; xi < 4; ++xi) {
            union { __hip_bfloat162 h2[2]; uint2 u; } gA, gB;
            gA.h2[0] = __float22bfloat162_rn(make_float2(A0[xi], A1[xi]));
            gA.h2[1] = __float22bfloat162_rn(make_float2(A2[xi], A3[xi]));
            gB.h2[0] = __float22bfloat162_rn(make_float2(B0[xi], B1[xi]));
            gB.h2[1] = __float22bfloat162_rn(make_float2(B2[xi], B3[xi]));
            *(uint2*)(pl + woffA + xi * XSB) = gA.u;
            *(uint2*)(pl + woffB + xi * XSB) = gB.u;
        }
    };

    // ---- prologue: planes zr0-1 and zr0 (slot = (p+3)%3)
    STAGE(zr0 - 1, smem + ((zr0 + 2) % 3) * PLANE_B);
    STAGE(zr0,     smem + (zr0 % 3) * PLANE_B);

    f32x4 acc[4] = {};

    for (int zi = zr0; zi < zr0 + 8; ++zi) {
        __syncthreads();                        // ring slot (zi+1)%3 free
        STAGE(zi + 1, smem + ((zi + 1) % 3) * PLANE_B);
        __syncthreads();                        // staged planes visible

        const char* P[3] = { smem + ((zi + 2) % 3) * PLANE_B,   // plane zi-1
                             smem + ((zi    ) % 3) * PLANE_B,   // plane zi
                             smem + ((zi + 1) % 3) * PLANE_B }; // plane zi+1
#pragma unroll
        for (int dz = 0; dz < 3; ++dz) {
#pragma unroll
            for (int q = 0; q < 6; ++q) {
                const char* rowq = P[dz] + (yh * 4 + q) * ROWB;
#pragma unroll
                for (int dx = 0; dx < 3; ++dx) {
                    const int lx = n + dx + 3;
                    const int s8 = lx >> 2;
                    const char* rowp = rowq + lx * XSB;
                    union { short8 v; short4v h[2]; } xf;
                    xf.h[0] = *(const short4v*)(rowp + (((2 * quad + 0) ^ s8) << 3));
                    xf.h[1] = *(const short4v*)(rowp + (((2 * quad + 1) ^ s8) << 3));
#pragma unroll
                    for (int dy = 0; dy < 3; ++dy) {
                        const int r = q - dy;
                        if (r >= 0 && r < 4)
                            acc[r] = __builtin_amdgcn_mfma_f32_16x16x32_bf16(
                                wreg[dz * 9 + dy * 3 + dx], xf.v, acc[r], 0, 0, 0);
                    }
                }
            }
        }

        // write output z = zi; reset acc
#pragma unroll
        for (int r = 0; r < 4; ++r) {
#pragma unroll
            for (int j = 0; j < 4; ++j)
                outb[(size_t)j * 65536 + (size_t)zi * 4096 + r * 64] =
                    rwb * acc[r][j] + bb[j];
            acc[r] = f32x4{0, 0, 0, 0};
        }
    }
}

// ---------------------------------------------------------------------------
extern "C" void kernel_launch(void* const* d_in, const int* in_sizes, int n_in,
                              void* d_out, int out_size, void* d_ws, size_t ws_size,
                              hipStream_t stream) {
    const float* x      = (const float*)d_in[0];  // [8,32,16,64,64]
    const float* rw     = (const float*)d_in[1];  // [8,8]
    const float* weight = (const float*)d_in[2];  // [8,32,32,27]
    const float* bias   = (const float*)d_in[3];  // [8,32]
    float* out = (float*)d_out;
    char*  ws  = (char*)d_ws;

    condconv_prep<<<109, 256, 0, stream>>>(rw, weight, bias, ws);
    // 512 blocks = 8 b x 8 y-tiles x 4 x-chunks x 2 z-halves (XCD-swizzled).
    condconv_zwalk<<<512, 256, 0, stream>>>(
        x, ws + WF_OFF,
        (const float*)(ws + RWB_OFF), (const float*)(ws + RWS_OFF), out);
}

// Round 9
// 145.183 us; speedup vs baseline: 1.1687x; 1.0259x over previous
//
#include <hip/hip_runtime.h>
#include <hip/hip_bf16.h>

typedef short short8 __attribute__((ext_vector_type(8)));
typedef float f32x4 __attribute__((ext_vector_type(4)));

// Workspace byte offsets
#define WF_OFF  0u        // bf16 wfrag[t=27][ot=2][lane=64][j=8] = 55296 B
#define RWB_OFF 55296u    // f32 rw_sum[b]*bias_sum[o] : [8][32] = 1024 B
#define RWS_OFF 56320u    // f32 rw_sum[8] = 32 B

// Ring-4 LDS planes. Plane = 10 y-rows x 24 X-cols x 80 B (64 B data = 4
// chunks of 16 B (8 c each), 16 B pad; chunk' = cc ^ (col&3)).
// ROWB = 24*80+16 = 1936 -> ROWB/4 = 484 === 4 (mod 8): the syp term walks all
// eight 4-bank positions; col*20 mod 32 spreads writes/reads across banks.
#define XSB 80
#define ROWB 1936
#define PLANE_B (10 * ROWB)    // 19360 B
#define RING_B (4 * PLANE_B)   // 77440 B  (2 blocks/CU: 154880 <= 163840)

__device__ __forceinline__ unsigned bf16rne(float f) {
    unsigned u = __float_as_uint(f);
    return (u + 0x7FFFu + ((u >> 16) & 1u)) >> 16;
}

// ---------------------------------------------------------------------------
// Prep: wfrag in MFMA A-operand layout; rwb_bias; rw_sum. (unchanged, proven)
// A-frag (16x16x32 bf16): lane l holds A[m=l&15][k=8*(l>>4)+j], j=0..7.
// wfrag byte addr = (dz*9+dy*3+dx)*2048 + ot*1024 + lane*16.
// ---------------------------------------------------------------------------
__global__ void condconv_prep(const float* __restrict__ rw,      // [8,8]
                              const float* __restrict__ weight,  // [8,32,32,27]
                              const float* __restrict__ bias,    // [8,32]
                              char* __restrict__ ws) {
    int i = blockIdx.x * 256 + threadIdx.x;
    if (i < 27648) {
        int t   = i >> 10;
        int rem = i & 1023;
        int ot  = rem >> 9;
        int l   = (rem >> 3) & 63;
        int j   = rem & 7;
        int o   = ot * 16 + (l & 15);
        int c   = 8 * (l >> 4) + j;
        float s = 0.f;
#pragma unroll
        for (int e = 0; e < 8; ++e) s += weight[((e * 32 + o) * 32 + c) * 27 + t];
        ((unsigned short*)(ws + WF_OFF))[i] = (unsigned short)bf16rne(s);
    } else if (i < 27904) {
        int k = i - 27648;
        int b = k >> 5, o = k & 31;
        float rs = 0.f, bs = 0.f;
#pragma unroll
        for (int e = 0; e < 8; ++e) { rs += rw[b * 8 + e]; bs += bias[e * 32 + o]; }
        ((float*)(ws + RWB_OFF))[k] = rs * bs;
        if (o == 0) ((float*)(ws + RWS_OFF))[b] = rs;
    }
}

// ---------------------------------------------------------------------------
// z-walk conv, z-step 2, ring-4. Block = (b, y8, x16, z-half); 4 bursts.
// Burst k: { barrier; stage planes zA+1, zA+2; barrier; compute outputs
// zA, zA+1 from the 4 resident planes }. One xf ds_read_b128 feeds both
// z-accumulators (up to 6 MFMA): 72 reads / 216 MFMA per wave per burst.
// 1 barrier-pair per z-output (was 2). wreg[27] hoisted. XCD swizzle: each
// XCD owns one b; 64 blocks walk z in lockstep -> planes stay L2-resident.
// ---------------------------------------------------------------------------
__global__ __launch_bounds__(256, 2) void condconv_zwalk2(
        const float* __restrict__ x,     // [8,32,16,64,64] fp32
        const char* __restrict__ wf,     // ws + WF_OFF
        const float* __restrict__ rwbias,
        const float* __restrict__ rwsum,
        float* __restrict__ out) {
    __shared__ __align__(16) char smem[RING_B];

    const int tid  = threadIdx.x;
    const int wv   = tid >> 6;
    const int lane = tid & 63;
    const int n    = lane & 15;
    const int quad = lane >> 4;
    const int ot   = wv & 1;
    const int yh   = wv >> 1;

    // 512 blocks, bijective XCD swizzle (512 % 8 == 0): b outermost.
    const int logical = (blockIdx.x & 7) * 64 + (blockIdx.x >> 3);
    const int b   = logical >> 6;
    const int rem = logical & 63;
    const int zb  = rem & 1;
    const int xb  = (rem >> 1) & 3;
    const int yb  = rem >> 3;
    const int y0 = yb * 8, x0 = xb * 16, zr0 = zb * 8;

    const float* xbp = x + (size_t)b * 2097152;   // 32*16*64*64

    // ---- staging map: 240 active threads = scc(4) x syp(10) x sx4(6).
    // Thread: c-chunk scc (8 c), plane-row syp, x-quad sx4 (4 cols).
    const bool sact = tid < 240;
    const int  scc  = tid / 60;                   // 0..3
    const int  rr   = tid % 60;
    const int  syp  = rr / 6;                     // 0..9
    const int  sx4  = rr % 6;                     // 0..5
    const int  gxq  = xb * 4 + sx4 - 1;           // global x-quad
    const int  gy   = y0 + syp - 1;
    const bool gok  = ((unsigned)gxq < 16u) && ((unsigned)gy < 64u);
    const long soff = (long)scc * 524288 +        // 8 c-planes per chunk
                      (long)(gok ? gy : 0) * 64 + (long)(gok ? gxq : 0) * 4;
    const int  wbase_off = syp * ROWB + (4 * sx4) * XSB;

    // ---- hoisted weight fragments: 27 taps for this wave's o-tile.
    short8 wreg[27];
    {
        const char* wb_ = wf + lane * 16 + ot * 1024;
#pragma unroll
        for (int t = 0; t < 27; ++t) wreg[t] = *(const short8*)(wb_ + t * 2048);
    }

    // ---- epilogue constants
    const float rwb = rwsum[b];
    float bb[4];
#pragma unroll
    for (int j = 0; j < 4; ++j) bb[j] = rwbias[b * 32 + ot * 16 + quad * 4 + j];
    float* outb = out + (size_t)(b * 32 + ot * 16 + quad * 4) * 65536 +
                  (size_t)(y0 + yh * 4) * 64 + x0 + n;

    // ---- stage plane p (OOB -> zeros) into ring slot (p&3).
    auto STAGE = [&](int p) {
        if (!sact) return;
        char* pl = smem + (p & 3) * PLANE_B;
        float a[8][4];
        if (gok && (unsigned)p < 16u) {
            const float* q0 = xbp + soff + (long)p * 4096;
#pragma unroll
            for (int k = 0; k < 8; ++k) {
                const float4 v = *(const float4*)(q0 + (size_t)k * 65536);
                a[k][0] = v.x; a[k][1] = v.y; a[k][2] = v.z; a[k][3] = v.w;
            }
        } else {
#pragma unroll
            for (int k = 0; k < 8; ++k)
                { a[k][0] = 0.f; a[k][1] = 0.f; a[k][2] = 0.f; a[k][3] = 0.f; }
        }
#pragma unroll
        for (int xi = 0; xi < 4; ++xi) {
            union { __hip_bfloat162 h2[4]; uint4 u; } g;
            g.h2[0] = __float22bfloat162_rn(make_float2(a[0][xi], a[1][xi]));
            g.h2[1] = __float22bfloat162_rn(make_float2(a[2][xi], a[3][xi]));
            g.h2[2] = __float22bfloat162_rn(make_float2(a[4][xi], a[5][xi]));
            g.h2[3] = __float22bfloat162_rn(make_float2(a[6][xi], a[7][xi]));
            const int col = 4 * sx4 + xi;
            *(uint4*)(pl + wbase_off + xi * XSB + ((scc ^ (col & 3)) << 4)) = g.u;
        }
    };

    // ---- prologue: planes zr0-1, zr0 (slots 3, 0)
    STAGE(zr0 - 1);
    STAGE(zr0);

    f32x4 accA[4] = {}, accB[4] = {};

#pragma unroll 1
    for (int k = 0; k < 4; ++k) {
        const int zA = zr0 + 2 * k;

        __syncthreads();                        // prior burst's reads done
        STAGE(zA + 1);
        STAGE(zA + 2);
        __syncthreads();                        // all 4 planes visible

#pragma unroll
        for (int pi = 0; pi < 4; ++pi) {
            const char* Pp = smem + ((zA - 1 + pi) & 3) * PLANE_B;
#pragma unroll
            for (int q = 0; q < 6; ++q) {
                const char* rowq = Pp + (yh * 4 + q) * ROWB;
#pragma unroll
                for (int dx = 0; dx < 3; ++dx) {
                    const int lx = n + dx + 3;
                    const short8 xf = *(const short8*)(
                        rowq + lx * XSB + ((quad ^ (lx & 3)) << 4));
#pragma unroll
                    for (int dy = 0; dy < 3; ++dy) {
                        const int r = q - dy;
                        if (r >= 0 && r < 4) {
                            if (pi < 3)
                                accA[r] = __builtin_amdgcn_mfma_f32_16x16x32_bf16(
                                    wreg[pi * 9 + dy * 3 + dx], xf, accA[r], 0, 0, 0);
                            if (pi > 0)
                                accB[r] = __builtin_amdgcn_mfma_f32_16x16x32_bf16(
                                    wreg[(pi - 1) * 9 + dy * 3 + dx], xf, accB[r], 0, 0, 0);
                        }
                    }
                }
            }
        }

        // write outputs zA (accA), zA+1 (accB); reset
#pragma unroll
        for (int r = 0; r < 4; ++r) {
#pragma unroll
            for (int j = 0; j < 4; ++j) {
                float* po = outb + (size_t)j * 65536 + r * 64;
                po[(size_t)zA * 4096]       = rwb * accA[r][j] + bb[j];
                po[(size_t)(zA + 1) * 4096] = rwb * accB[r][j] + bb[j];
            }
            accA[r] = f32x4{0, 0, 0, 0};
            accB[r] = f32x4{0, 0, 0, 0};
        }
    }
}

// ---------------------------------------------------------------------------
extern "C" void kernel_launch(void* const* d_in, const int* in_sizes, int n_in,
                              void* d_out, int out_size, void* d_ws, size_t ws_size,
                              hipStream_t stream) {
    const float* x      = (const float*)d_in[0];  // [8,32,16,64,64]
    const float* rw     = (const float*)d_in[1];  // [8,8]
    const float* weight = (const float*)d_in[2];  // [8,32,32,27]
    const float* bias   = (const float*)d_in[3];  // [8,32]
    float* out = (float*)d_out;
    char*  ws  = (char*)d_ws;

    condconv_prep<<<109, 256, 0, stream>>>(rw, weight, bias, ws);
    // 512 blocks = 8 b x 8 y-tiles x 4 x-chunks x 2 z-halves (XCD-swizzled).
    condconv_zwalk2<<<512, 256, 0, stream>>>(
        x, ws + WF_OFF,
        (const float*)(ws + RWB_OFF), (const float*)(ws + RWS_OFF), out);
}

// Round 10
// 144.339 us; speedup vs baseline: 1.1755x; 1.0059x over previous
//
#include <hip/hip_runtime.h>
#include <hip/hip_bf16.h>

typedef short short8 __attribute__((ext_vector_type(8)));
typedef float f32x4 __attribute__((ext_vector_type(4)));

// Workspace byte offsets
#define WF_OFF  0u        // bf16 wfrag[t=27][ot=2][lane=64][j=8] = 55296 B
#define RWB_OFF 55296u    // f32 rw_sum[b]*bias_sum[o] : [8][32] = 1024 B
#define RWS_OFF 56320u    // f32 rw_sum[8] = 32 B

// Ring-4 LDS planes, CHUNK-MAJOR rows: row = [chunk 0..3][col 0..23] x 16 B.
// chunk stride 384 B (384/4 === 0 mod 32: quad term drops out of bank index);
// row stride 1552 B (= 1536 + 16 pad; 388 === 4 mod 32: syp spreads writes).
// Read addr = quad*384 + lx*16 -> bank 4*lx mod 32: 8 consecutive lanes tile
// all 32 banks exactly -> conflict-free b128 reads, NO swizzle either side.
#define CHS 384
#define RB  1552
#define PLANE_B (10 * RB)      // 15520 B
#define RING_B (4 * PLANE_B)   // 62080 B  (2 blocks/CU: 124160 <= 163840)

__device__ __forceinline__ unsigned bf16rne(float f) {
    unsigned u = __float_as_uint(f);
    return (u + 0x7FFFu + ((u >> 16) & 1u)) >> 16;
}

// ---------------------------------------------------------------------------
// Prep: wfrag in MFMA A-operand layout; rwb_bias; rw_sum. (unchanged, proven)
// A-frag (16x16x32 bf16): lane l holds A[m=l&15][k=8*(l>>4)+j], j=0..7.
// wfrag byte addr = (dz*9+dy*3+dx)*2048 + ot*1024 + lane*16.
// ---------------------------------------------------------------------------
__global__ void condconv_prep(const float* __restrict__ rw,      // [8,8]
                              const float* __restrict__ weight,  // [8,32,32,27]
                              const float* __restrict__ bias,    // [8,32]
                              char* __restrict__ ws) {
    int i = blockIdx.x * 256 + threadIdx.x;
    if (i < 27648) {
        int t   = i >> 10;
        int rem = i & 1023;
        int ot  = rem >> 9;
        int l   = (rem >> 3) & 63;
        int j   = rem & 7;
        int o   = ot * 16 + (l & 15);
        int c   = 8 * (l >> 4) + j;
        float s = 0.f;
#pragma unroll
        for (int e = 0; e < 8; ++e) s += weight[((e * 32 + o) * 32 + c) * 27 + t];
        ((unsigned short*)(ws + WF_OFF))[i] = (unsigned short)bf16rne(s);
    } else if (i < 27904) {
        int k = i - 27648;
        int b = k >> 5, o = k & 31;
        float rs = 0.f, bs = 0.f;
#pragma unroll
        for (int e = 0; e < 8; ++e) { rs += rw[b * 8 + e]; bs += bias[e * 32 + o]; }
        ((float*)(ws + RWB_OFF))[k] = rs * bs;
        if (o == 0) ((float*)(ws + RWS_OFF))[b] = rs;
    }
}

// ---------------------------------------------------------------------------
// z-walk conv, z-step 2, ring-4, chunk-major LDS. Block = (b, y8, x16,
// z-half); 4 bursts of { barrier; stage 2 planes; barrier; 216 MFMA/wave }.
// One conflict-free ds_read_b128 feeds up to 6 MFMA (2 z-outputs x 3 dy).
// wreg[27] hoisted. XCD swizzle: each XCD owns one b; its 64 blocks walk z
// in lockstep -> 3-plane working set stays L2-resident (FETCH ~37 MB).
// ---------------------------------------------------------------------------
__global__ __launch_bounds__(256, 2) void condconv_zwalk3(
        const float* __restrict__ x,     // [8,32,16,64,64] fp32
        const char* __restrict__ wf,     // ws + WF_OFF
        const float* __restrict__ rwbias,
        const float* __restrict__ rwsum,
        float* __restrict__ out) {
    __shared__ __align__(16) char smem[RING_B];

    const int tid  = threadIdx.x;
    const int wv   = tid >> 6;
    const int lane = tid & 63;
    const int n    = lane & 15;
    const int quad = lane >> 4;
    const int ot   = wv & 1;
    const int yh   = wv >> 1;

    // 512 blocks, bijective XCD swizzle (512 % 8 == 0): b outermost.
    const int logical = (blockIdx.x & 7) * 64 + (blockIdx.x >> 3);
    const int b   = logical >> 6;
    const int rem = logical & 63;
    const int zb  = rem & 1;
    const int xb  = (rem >> 1) & 3;
    const int yb  = rem >> 3;
    const int y0 = yb * 8, x0 = xb * 16, zr0 = zb * 8;

    const float* xbp = x + (size_t)b * 2097152;   // 32*16*64*64

    // ---- staging map: 240 active threads = scc(4) x syp(10) x sx4(6).
    // Thread: c-chunk scc (8 c), plane-row syp, x-quad sx4 (4 cols).
    const bool sact = tid < 240;
    const int  scc  = tid / 60;                   // 0..3
    const int  rr   = tid % 60;
    const int  syp  = rr / 6;                     // 0..9
    const int  sx4  = rr % 6;                     // 0..5
    const int  gxq  = xb * 4 + sx4 - 1;           // global x-quad
    const int  gy   = y0 + syp - 1;
    const bool gok  = ((unsigned)gxq < 16u) && ((unsigned)gy < 64u);
    const long soff = (long)scc * 524288 +        // 8 c-planes per chunk
                      (long)(gok ? gy : 0) * 64 + (long)(gok ? gxq : 0) * 4;
    const int  woff = syp * RB + scc * CHS + (4 * sx4) * 16;

    // ---- hoisted weight fragments: 27 taps for this wave's o-tile.
    short8 wreg[27];
    {
        const char* wb_ = wf + lane * 16 + ot * 1024;
#pragma unroll
        for (int t = 0; t < 27; ++t) wreg[t] = *(const short8*)(wb_ + t * 2048);
    }

    // ---- epilogue constants
    const float rwb = rwsum[b];
    float bb[4];
#pragma unroll
    for (int j = 0; j < 4; ++j) bb[j] = rwbias[b * 32 + ot * 16 + quad * 4 + j];
    float* outb = out + (size_t)(b * 32 + ot * 16 + quad * 4) * 65536 +
                  (size_t)(y0 + yh * 4) * 64 + x0 + n;

    // ---- stage plane p (OOB -> zeros) into ring slot (p&3).
    auto STAGE = [&](int p) {
        if (!sact) return;
        char* pl = smem + (p & 3) * PLANE_B;
        float a[8][4];
        if (gok && (unsigned)p < 16u) {
            const float* q0 = xbp + soff + (long)p * 4096;
#pragma unroll
            for (int k = 0; k < 8; ++k) {
                const float4 v = *(const float4*)(q0 + (size_t)k * 65536);
                a[k][0] = v.x; a[k][1] = v.y; a[k][2] = v.z; a[k][3] = v.w;
            }
        } else {
#pragma unroll
            for (int k = 0; k < 8; ++k)
                { a[k][0] = 0.f; a[k][1] = 0.f; a[k][2] = 0.f; a[k][3] = 0.f; }
        }
#pragma unroll
        for (int xi = 0; xi < 4; ++xi) {
            union { __hip_bfloat162 h2[4]; uint4 u; } g;
            g.h2[0] = __float22bfloat162_rn(make_float2(a[0][xi], a[1][xi]));
            g.h2[1] = __float22bfloat162_rn(make_float2(a[2][xi], a[3][xi]));
            g.h2[2] = __float22bfloat162_rn(make_float2(a[4][xi], a[5][xi]));
            g.h2[3] = __float22bfloat162_rn(make_float2(a[6][xi], a[7][xi]));
            *(uint4*)(pl + woff + xi * 16) = g.u;
        }
    };

    // ---- prologue: planes zr0-1, zr0 (slots 3, 0)
    STAGE(zr0 - 1);
    STAGE(zr0);

    f32x4 accA[4] = {}, accB[4] = {};

#pragma unroll 1
    for (int k = 0; k < 4; ++k) {
        const int zA = zr0 + 2 * k;

        __syncthreads();                        // prior burst's reads done
        STAGE(zA + 1);
        STAGE(zA + 2);
        __syncthreads();                        // all 4 planes visible

#pragma unroll
        for (int pi = 0; pi < 4; ++pi) {
            const char* Pp = smem + ((zA - 1 + pi) & 3) * PLANE_B;
#pragma unroll
            for (int q = 0; q < 6; ++q) {
                const char* rowq = Pp + (yh * 4 + q) * RB + quad * CHS;
#pragma unroll
                for (int dx = 0; dx < 3; ++dx) {
                    const int lx = n + dx + 3;
                    const short8 xf = *(const short8*)(rowq + lx * 16);
#pragma unroll
                    for (int dy = 0; dy < 3; ++dy) {
                        const int r = q - dy;
                        if (r >= 0 && r < 4) {
                            if (pi < 3)
                                accA[r] = __builtin_amdgcn_mfma_f32_16x16x32_bf16(
                                    wreg[pi * 9 + dy * 3 + dx], xf, accA[r], 0, 0, 0);
                            if (pi > 0)
                                accB[r] = __builtin_amdgcn_mfma_f32_16x16x32_bf16(
                                    wreg[(pi - 1) * 9 + dy * 3 + dx], xf, accB[r], 0, 0, 0);
                        }
                    }
                }
            }
        }

        // write outputs zA (accA), zA+1 (accB); reset
#pragma unroll
        for (int r = 0; r < 4; ++r) {
#pragma unroll
            for (int j = 0; j < 4; ++j) {
                float* po = outb + (size_t)j * 65536 + r * 64;
                po[(size_t)zA * 4096]       = rwb * accA[r][j] + bb[j];
                po[(size_t)(zA + 1) * 4096] = rwb * accB[r][j] + bb[j];
            }
            accA[r] = f32x4{0, 0, 0, 0};
            accB[r] = f32x4{0, 0, 0, 0};
        }
    }
}

// ---------------------------------------------------------------------------
extern "C" void kernel_launch(void* const* d_in, const int* in_sizes, int n_in,
                              void* d_out, int out_size, void* d_ws, size_t ws_size,
                              hipStream_t stream) {
    const float* x      = (const float*)d_in[0];  // [8,32,16,64,64]
    const float* rw     = (const float*)d_in[1];  // [8,8]
    const float* weight = (const float*)d_in[2];  // [8,32,32,27]
    const float* bias   = (const float*)d_in[3];  // [8,32]
    float* out = (float*)d_out;
    char*  ws  = (char*)d_ws;

    condconv_prep<<<109, 256, 0, stream>>>(rw, weight, bias, ws);
    // 512 blocks = 8 b x 8 y-tiles x 4 x-chunks x 2 z-halves (XCD-swizzled).
    condconv_zwalk3<<<512, 256, 0, stream>>>(
        x, ws + WF_OFF,
        (const float*)(ws + RWB_OFF), (const float*)(ws + RWS_OFF), out);
}